// Round 3
// baseline (1908.870 us; speedup 1.0000x reference)
//
#include <hip/hip_runtime.h>
#include <math.h>

#define N_NODES 50000
#define N_EDGES 400000
#define F_DIM   128
#define N_RBF   20
#define SCAN_B  256
#define N_CHUNK ((N_NODES + SCAN_B - 1) / SCAN_B)   // 196

// ---------------------------------------------------------------------------
// phi_table[t] = silu(emb_table[t] @ w_phi1 + b_phi1) @ w_phi2 + b_phi2
// 384 threads/block: phase1 uses 128, phase2 all 384 (one output each).
// ---------------------------------------------------------------------------
__global__ void phi_table_kernel(const float* __restrict__ emb_table,
                                 const float* __restrict__ w_phi1,
                                 const float* __restrict__ b_phi1,
                                 const float* __restrict__ w_phi2,
                                 const float* __restrict__ b_phi2,
                                 float* __restrict__ phi_table) {
    __shared__ float emb_s[F_DIM];
    __shared__ float h_s[F_DIM];
    const int t = blockIdx.x;
    const int o = threadIdx.x;
    if (o < F_DIM) emb_s[o] = emb_table[t * F_DIM + o];
    __syncthreads();
    if (o < F_DIM) {
        float acc = b_phi1[o];
#pragma unroll 8
        for (int k = 0; k < F_DIM; ++k)
            acc = fmaf(emb_s[k], w_phi1[k * F_DIM + o], acc);
        h_s[o] = acc / (1.0f + expf(-acc));   // silu
    }
    __syncthreads();
    float a2 = b_phi2[o];
#pragma unroll 8
    for (int k = 0; k < F_DIM; ++k)
        a2 = fmaf(h_s[k], w_phi2[k * (3 * F_DIM) + o], a2);
    phi_table[t * (3 * F_DIM) + o] = a2;
}

// ---------------------------------------------------------------------------
// zero counts + transpose w_rbf [20][384] -> wt [384][20]
// ---------------------------------------------------------------------------
__global__ void prep_kernel(const float* __restrict__ w_rbf,
                            int* __restrict__ counts,
                            float* __restrict__ wt) {
    const int idx = blockIdx.x * blockDim.x + threadIdx.x;
    if (idx < N_NODES) counts[idx] = 0;
    if (idx < 3 * F_DIM) {
#pragma unroll
        for (int n = 0; n < N_RBF; ++n)
            wt[idx * N_RBF + n] = w_rbf[n * (3 * F_DIM) + idx];
    }
}

__global__ void count_kernel(const int* __restrict__ edst, int* __restrict__ counts) {
    const int e = blockIdx.x * blockDim.x + threadIdx.x;
    if (e < N_EDGES) atomicAdd(&counts[edst[e]], 1);
}

__global__ void scan_partial_kernel(const int* __restrict__ counts,
                                    int* __restrict__ partial,
                                    int* __restrict__ chunk_sums) {
    __shared__ int s[SCAN_B];
    const int tid = threadIdx.x;
    const int gid = blockIdx.x * SCAN_B + tid;
    const int v = (gid < N_NODES) ? counts[gid] : 0;
    s[tid] = v;
    __syncthreads();
    for (int d = 1; d < SCAN_B; d <<= 1) {
        const int t = (tid >= d) ? s[tid - d] : 0;
        __syncthreads();
        s[tid] += t;
        __syncthreads();
    }
    if (gid < N_NODES) partial[gid] = s[tid] - v;
    if (tid == SCAN_B - 1) chunk_sums[blockIdx.x] = s[tid];
}

__global__ void scan_sums_kernel(int* __restrict__ chunk_sums,
                                 int* __restrict__ chunk_pref) {
    __shared__ int s[SCAN_B];
    const int tid = threadIdx.x;
    const int v = (tid < N_CHUNK) ? chunk_sums[tid] : 0;
    s[tid] = v;
    __syncthreads();
    for (int d = 1; d < SCAN_B; d <<= 1) {
        const int t = (tid >= d) ? s[tid - d] : 0;
        __syncthreads();
        s[tid] += t;
        __syncthreads();
    }
    if (tid < N_CHUNK) chunk_pref[tid] = s[tid] - v;
}

__global__ void finalize_offsets_kernel(const int* __restrict__ partial,
                                        const int* __restrict__ chunk_pref,
                                        int* __restrict__ offsets,
                                        int* __restrict__ cursor) {
    const int i = blockIdx.x * blockDim.x + threadIdx.x;
    if (i >= N_NODES) return;
    const int o = partial[i] + chunk_pref[i >> 8];
    offsets[i] = o;
    cursor[i]  = o;
}

// ---------------------------------------------------------------------------
// Edge-parallel precompute fused with CSR fill: all random gathers happen
// here (fully parallel, latency-hidden). rbf via Chebyshev recurrence.
// Writes (px,py,pz,d), (j, z[j]), rbf[20] at the edge's CSR slot.
// ---------------------------------------------------------------------------
__global__ void edge_pre_kernel(const float* __restrict__ pos,
                                const int* __restrict__ z,
                                const int* __restrict__ esrc,
                                const int* __restrict__ edst,
                                int* __restrict__ cursor,
                                float4* __restrict__ edata,
                                int2* __restrict__ jt,
                                float* __restrict__ rw) {
    const int e = blockIdx.x * blockDim.x + threadIdx.x;
    if (e >= N_EDGES) return;
    const int j = esrc[e];
    const int i = edst[e];
    const int p = atomicAdd(&cursor[i], 1);

    const float px = pos[3 * i + 0] - pos[3 * j + 0];
    const float py = pos[3 * i + 1] - pos[3 * j + 1];
    const float pz = pos[3 * i + 2] - pos[3 * j + 2];
    const float d = sqrtf(px * px + py * py + pz * pz);
    const float inv_d = 1.0f / d;

    float sa, ca;
    sincosf(0.6283185307179586f * d, &sa, &ca);   // pi*d/5
    const float twoc = 2.0f * ca;
    float rb[N_RBF];
    float sm1 = 0.0f, s0 = sa;                    // sin(n*a) recurrence
#pragma unroll
    for (int n = 0; n < N_RBF; ++n) {
        rb[n] = s0 * inv_d;
        const float s1 = fmaf(twoc, s0, -sm1);
        sm1 = s0; s0 = s1;
    }

    edata[p] = make_float4(px, py, pz, d);
    jt[p]    = make_int2(j, z[j]);
    float4* rp = (float4*)(rw + (size_t)p * N_RBF);
#pragma unroll
    for (int q = 0; q < 5; ++q)
        rp[q] = make_float4(rb[4 * q], rb[4 * q + 1], rb[4 * q + 2], rb[4 * q + 3]);
}

// ---------------------------------------------------------------------------
// Gather: one 64-lane wave per node; each thread owns f and f+64.
// W-columns from transposed wt via float4 loads + float4 FMAs.
// Distance-1 prefetch of the per-edge broadcast data.
// ---------------------------------------------------------------------------
__device__ __forceinline__ float4 f4fma(float4 a, float4 b, float4 c) {
    return make_float4(fmaf(a.x, b.x, c.x), fmaf(a.y, b.y, c.y),
                       fmaf(a.z, b.z, c.z), fmaf(a.w, b.w, c.w));
}
__device__ __forceinline__ float dot20(float4 r0, float4 r1, float4 r2,
                                       float4 r3, float4 r4,
                                       const float4* __restrict__ w) {
    float4 acc = make_float4(r0.x * w[0].x, r0.y * w[0].y, r0.z * w[0].z, r0.w * w[0].w);
    acc = f4fma(r1, w[1], acc);
    acc = f4fma(r2, w[2], acc);
    acc = f4fma(r3, w[3], acc);
    acc = f4fma(r4, w[4], acc);
    return (acc.x + acc.y) + (acc.z + acc.w);
}

__global__ void gather_kernel(const float* __restrict__ eq,
                              const float* __restrict__ emb_table,
                              const float* __restrict__ phi_table,
                              const float* __restrict__ wt,
                              const float* __restrict__ b_rbf,
                              const int* __restrict__ z,
                              const float4* __restrict__ edata,
                              const int2* __restrict__ jt,
                              const float* __restrict__ rw,
                              const int* __restrict__ offsets,
                              const int* __restrict__ counts,
                              float* __restrict__ out_emb,
                              float* __restrict__ out_eq) {
    const int lane = threadIdx.x & 63;
    const int wv   = threadIdx.x >> 6;
    const int i    = blockIdx.x * 4 + wv;
    if (i >= N_NODES) return;

    const int start = offsets[i];
    const int cnt   = counts[i];
    const int f0 = lane, f1 = lane + 64;

    const float br10 = b_rbf[f0],           br11 = b_rbf[f1];
    const float br20 = b_rbf[F_DIM + f0],   br21 = b_rbf[F_DIM + f1];
    const float br30 = b_rbf[2*F_DIM + f0], br31 = b_rbf[2*F_DIM + f1];

    const float4* w10 = (const float4*)(wt + (0 * F_DIM + f0) * N_RBF);
    const float4* w11 = (const float4*)(wt + (0 * F_DIM + f1) * N_RBF);
    const float4* w20 = (const float4*)(wt + (1 * F_DIM + f0) * N_RBF);
    const float4* w21 = (const float4*)(wt + (1 * F_DIM + f1) * N_RBF);
    const float4* w30 = (const float4*)(wt + (2 * F_DIM + f0) * N_RBF);
    const float4* w31 = (const float4*)(wt + (2 * F_DIM + f1) * N_RBF);

    float accE0 = 0.f, accE1 = 0.f;
    float ax0 = 0.f, ay0 = 0.f, az0 = 0.f;
    float ax1 = 0.f, ay1 = 0.f, az1 = 0.f;

    int2   cjt;
    float4 cpd;
    if (cnt > 0) { cjt = jt[start]; cpd = edata[start]; }

    for (int k = 0; k < cnt; ++k) {
        const int p = start + k;
        const int j = cjt.x;
        const int t = cjt.y;
        const float4 pd = cpd;
        if (k + 1 < cnt) { cjt = jt[p + 1]; cpd = edata[p + 1]; }

        const float4* rp = (const float4*)(rw + (size_t)p * N_RBF);
        const float4 r0 = rp[0], r1 = rp[1], r2 = rp[2], r3 = rp[3], r4 = rp[4];

        const float* pt = phi_table + t * (3 * F_DIM);
        const float phi10 = pt[f0],           phi11 = pt[f1];
        const float phi20 = pt[F_DIM + f0],   phi21 = pt[F_DIM + f1];
        const float phi30 = pt[2*F_DIM + f0], phi31 = pt[2*F_DIM + f1];

        const float* ej = eq + (size_t)j * (F_DIM * 3);
        const float e00 = ej[f0*3+0], e01 = ej[f0*3+1], e02 = ej[f0*3+2];
        const float e10 = ej[f1*3+0], e11 = ej[f1*3+1], e12 = ej[f1*3+2];

        const float W10 = dot20(r0, r1, r2, r3, r4, w10) + br10;
        const float W11 = dot20(r0, r1, r2, r3, r4, w11) + br11;
        const float W20 = dot20(r0, r1, r2, r3, r4, w20) + br20;
        const float W21 = dot20(r0, r1, r2, r3, r4, w21) + br21;
        const float W30 = dot20(r0, r1, r2, r3, r4, w30) + br30;
        const float W31 = dot20(r0, r1, r2, r3, r4, w31) + br31;

        accE0 += phi10 * W10;
        accE1 += phi11 * W11;
        const float s20 = phi20 * W20;
        const float s21 = phi21 * W21;
        const float s30 = phi30 * W30 * pd.w;
        const float s31 = phi31 * W31 * pd.w;

        ax0 = fmaf(e00, s20, fmaf(s30, pd.x, ax0));
        ay0 = fmaf(e01, s20, fmaf(s30, pd.y, ay0));
        az0 = fmaf(e02, s20, fmaf(s30, pd.z, az0));
        ax1 = fmaf(e10, s21, fmaf(s31, pd.x, ax1));
        ay1 = fmaf(e11, s21, fmaf(s31, pd.y, ay1));
        az1 = fmaf(e12, s21, fmaf(s31, pd.z, az1));
    }

    const int zi = z[i];
    out_emb[(size_t)i * F_DIM + f0] = emb_table[zi * F_DIM + f0] + accE0;
    out_emb[(size_t)i * F_DIM + f1] = emb_table[zi * F_DIM + f1] + accE1;

    const float* ei = eq     + (size_t)i * (F_DIM * 3);
    float*       od = out_eq + (size_t)i * (F_DIM * 3);
    od[f0*3+0] = ei[f0*3+0] + ax0;
    od[f0*3+1] = ei[f0*3+1] + ay0;
    od[f0*3+2] = ei[f0*3+2] + az0;
    od[f1*3+0] = ei[f1*3+0] + ax1;
    od[f1*3+1] = ei[f1*3+1] + ay1;
    od[f1*3+2] = ei[f1*3+2] + az1;
}

// ---------------------------------------------------------------------------
extern "C" void kernel_launch(void* const* d_in, const int* in_sizes, int n_in,
                              void* d_out, int out_size, void* d_ws, size_t ws_size,
                              hipStream_t stream) {
    const float* pos       = (const float*)d_in[0];
    const float* eq        = (const float*)d_in[1];
    const float* emb_table = (const float*)d_in[2];
    const float* w_phi1    = (const float*)d_in[3];
    const float* b_phi1    = (const float*)d_in[4];
    const float* w_phi2    = (const float*)d_in[5];
    const float* b_phi2    = (const float*)d_in[6];
    const float* w_rbf     = (const float*)d_in[7];
    const float* b_rbf     = (const float*)d_in[8];
    const int*   z         = (const int*)d_in[9];
    const int*   esrc      = (const int*)d_in[10];
    const int*   edst      = (const int*)d_in[11];

    float* out_emb = (float*)d_out;                               // [N, F]
    float* out_eq  = (float*)d_out + (size_t)N_NODES * F_DIM;     // [N, F, 3]

    // workspace layout (16B-aligned chunks)
    char* ws = (char*)d_ws;
    float4* edata     = (float4*)ws;   ws += (size_t)N_EDGES * 16;
    float*  rw        = (float*)ws;    ws += (size_t)N_EDGES * N_RBF * 4;
    int2*   jt        = (int2*)ws;     ws += (size_t)N_EDGES * 8;
    float*  phi_table = (float*)ws;    ws += 100 * 3 * F_DIM * 4;
    float*  wt        = (float*)ws;    ws += 3 * F_DIM * N_RBF * 4;
    int*    counts    = (int*)ws;      ws += N_NODES * 4;
    int*    partial   = (int*)ws;      ws += N_NODES * 4;
    int*    offsets   = (int*)ws;      ws += N_NODES * 4;
    int*    cursor    = (int*)ws;      ws += N_NODES * 4;
    int*    chunk_sums= (int*)ws;      ws += SCAN_B * 4;
    int*    chunk_pref= (int*)ws;      ws += SCAN_B * 4;

    phi_table_kernel<<<100, 3 * F_DIM, 0, stream>>>(emb_table, w_phi1, b_phi1,
                                                    w_phi2, b_phi2, phi_table);
    prep_kernel<<<(N_NODES + 255) / 256, 256, 0, stream>>>(w_rbf, counts, wt);
    count_kernel<<<(N_EDGES + 255) / 256, 256, 0, stream>>>(edst, counts);
    scan_partial_kernel<<<N_CHUNK, SCAN_B, 0, stream>>>(counts, partial, chunk_sums);
    scan_sums_kernel<<<1, SCAN_B, 0, stream>>>(chunk_sums, chunk_pref);
    finalize_offsets_kernel<<<(N_NODES + 255) / 256, 256, 0, stream>>>(
        partial, chunk_pref, offsets, cursor);
    edge_pre_kernel<<<(N_EDGES + 255) / 256, 256, 0, stream>>>(
        pos, z, esrc, edst, cursor, edata, jt, rw);
    gather_kernel<<<(N_NODES + 3) / 4, 256, 0, stream>>>(
        eq, emb_table, phi_table, wt, b_rbf, z, edata, jt, rw,
        offsets, counts, out_emb, out_eq);
}

// Round 4
// 553.529 us; speedup vs baseline: 3.4485x; 3.4485x over previous
//
#include <hip/hip_runtime.h>
#include <math.h>

#define N_NODES 50000
#define N_EDGES 400000
#define F_DIM   128
#define N_RBF   20
#define SCAN_B  256
#define N_CHUNK ((N_NODES + SCAN_B - 1) / SCAN_B)   // 196

// ---------------------------------------------------------------------------
// phi_table[t] = silu(emb_table[t] @ w_phi1 + b_phi1) @ w_phi2 + b_phi2
// ---------------------------------------------------------------------------
__global__ void phi_table_kernel(const float* __restrict__ emb_table,
                                 const float* __restrict__ w_phi1,
                                 const float* __restrict__ b_phi1,
                                 const float* __restrict__ w_phi2,
                                 const float* __restrict__ b_phi2,
                                 float* __restrict__ phi_table) {
    __shared__ float emb_s[F_DIM];
    __shared__ float h_s[F_DIM];
    const int t = blockIdx.x;
    const int o = threadIdx.x;
    if (o < F_DIM) emb_s[o] = emb_table[t * F_DIM + o];
    __syncthreads();
    if (o < F_DIM) {
        float acc = b_phi1[o];
#pragma unroll 8
        for (int k = 0; k < F_DIM; ++k)
            acc = fmaf(emb_s[k], w_phi1[k * F_DIM + o], acc);
        h_s[o] = acc / (1.0f + expf(-acc));   // silu
    }
    __syncthreads();
    float a2 = b_phi2[o];
#pragma unroll 8
    for (int k = 0; k < F_DIM; ++k)
        a2 = fmaf(h_s[k], w_phi2[k * (3 * F_DIM) + o], a2);
    phi_table[t * (3 * F_DIM) + o] = a2;
}

__global__ void count_kernel(const int* __restrict__ edst, int* __restrict__ counts) {
    const int e = blockIdx.x * blockDim.x + threadIdx.x;
    if (e < N_EDGES) atomicAdd(&counts[edst[e]], 1);
}

__global__ void scan_partial_kernel(const int* __restrict__ counts,
                                    int* __restrict__ partial,
                                    int* __restrict__ chunk_sums) {
    __shared__ int s[SCAN_B];
    const int tid = threadIdx.x;
    const int gid = blockIdx.x * SCAN_B + tid;
    const int v = (gid < N_NODES) ? counts[gid] : 0;
    s[tid] = v;
    __syncthreads();
    for (int d = 1; d < SCAN_B; d <<= 1) {
        const int t = (tid >= d) ? s[tid - d] : 0;
        __syncthreads();
        s[tid] += t;
        __syncthreads();
    }
    if (gid < N_NODES) partial[gid] = s[tid] - v;
    if (tid == SCAN_B - 1) chunk_sums[blockIdx.x] = s[tid];
}

__global__ void scan_sums_kernel(int* __restrict__ chunk_sums,
                                 int* __restrict__ chunk_pref) {
    __shared__ int s[SCAN_B];
    const int tid = threadIdx.x;
    const int v = (tid < N_CHUNK) ? chunk_sums[tid] : 0;
    s[tid] = v;
    __syncthreads();
    for (int d = 1; d < SCAN_B; d <<= 1) {
        const int t = (tid >= d) ? s[tid - d] : 0;
        __syncthreads();
        s[tid] += t;
        __syncthreads();
    }
    if (tid < N_CHUNK) chunk_pref[tid] = s[tid] - v;
}

__global__ void finalize_offsets_kernel(const int* __restrict__ partial,
                                        const int* __restrict__ chunk_pref,
                                        int* __restrict__ offsets,
                                        int* __restrict__ cursor) {
    const int i = blockIdx.x * blockDim.x + threadIdx.x;
    if (i >= N_NODES) return;
    const int o = partial[i] + chunk_pref[i >> 8];
    offsets[i] = o;
    cursor[i]  = o;
}

// ---------------------------------------------------------------------------
// Edge-parallel precompute + CSR fill: all random pointer-chasing happens
// here, fully parallel. rbf via Chebyshev (1 sincos + 19 FMA pairs).
// ---------------------------------------------------------------------------
__global__ void edge_pre_kernel(const float* __restrict__ pos,
                                const int* __restrict__ z,
                                const int* __restrict__ esrc,
                                const int* __restrict__ edst,
                                int* __restrict__ cursor,
                                float4* __restrict__ edata,
                                int2* __restrict__ jt,
                                float* __restrict__ rw) {
    const int e = blockIdx.x * blockDim.x + threadIdx.x;
    if (e >= N_EDGES) return;
    const int j = esrc[e];
    const int i = edst[e];
    const int p = atomicAdd(&cursor[i], 1);

    const float px = pos[3 * i + 0] - pos[3 * j + 0];
    const float py = pos[3 * i + 1] - pos[3 * j + 1];
    const float pz = pos[3 * i + 2] - pos[3 * j + 2];
    const float d = sqrtf(px * px + py * py + pz * pz);
    const float inv_d = 1.0f / d;

    float sa, ca;
    sincosf(0.6283185307179586f * d, &sa, &ca);   // pi*d/5
    const float twoc = 2.0f * ca;
    float rb[N_RBF];
    float sm1 = 0.0f, s0 = sa;                    // sin(n*a) recurrence
#pragma unroll
    for (int n = 0; n < N_RBF; ++n) {
        rb[n] = s0 * inv_d;
        const float s1 = fmaf(twoc, s0, -sm1);
        sm1 = s0; s0 = s1;
    }

    edata[p] = make_float4(px, py, pz, d);
    jt[p]    = make_int2(j, z[j]);
    float4* rp = (float4*)(rw + (size_t)p * N_RBF);
#pragma unroll
    for (int q = 0; q < 5; ++q)
        rp[q] = make_float4(rb[4 * q], rb[4 * q + 1], rb[4 * q + 2], rb[4 * q + 3]);
}

// ---------------------------------------------------------------------------
// Gather: 128-thread group per node (2 per block). Thread f owns output
// columns f, 128+f, 256+f. w_rbf read in original [n][384] layout ->
// stride-4 coalesced, L1-resident. rbf read as wave-uniform 80B broadcast.
// Distance-1 prefetch of jt/edata/eq[j] overlaps the next random gather
// with this edge's 60-FMA compute.
// ---------------------------------------------------------------------------
__global__ void gather_kernel(const float* __restrict__ eq,
                              const float* __restrict__ emb_table,
                              const float* __restrict__ phi_table,
                              const float* __restrict__ w_rbf,
                              const float* __restrict__ b_rbf,
                              const int* __restrict__ z,
                              const float4* __restrict__ edata,
                              const int2* __restrict__ jt,
                              const float* __restrict__ rw,
                              const int* __restrict__ offsets,
                              const int* __restrict__ counts,
                              float* __restrict__ out_emb,
                              float* __restrict__ out_eq) {
    const int tid = threadIdx.x;
    const int grp = tid >> 7;
    const int f   = tid & 127;
    const int i   = blockIdx.x * 2 + grp;
    if (i >= N_NODES) return;

    const int start = offsets[i];
    const int cnt   = counts[i];

    const float br1 = b_rbf[f];
    const float br2 = b_rbf[F_DIM + f];
    const float br3 = b_rbf[2 * F_DIM + f];

    float accE = 0.f, ax = 0.f, ay = 0.f, az = 0.f;

    int2   cjt;
    float4 cpd;
    float  ce0, ce1, ce2;
    if (cnt > 0) {
        cjt = jt[start];
        cpd = edata[start];
        const float* ej = eq + ((size_t)cjt.x * F_DIM + f) * 3;
        ce0 = ej[0]; ce1 = ej[1]; ce2 = ej[2];
    }

    for (int k = 0; k < cnt; ++k) {
        const int p = start + k;
        const int t = cjt.y;
        const float4 pd = cpd;
        const float e0 = ce0, e1 = ce1, e2 = ce2;

        // prefetch next edge (overlaps with the FMA block below)
        if (k + 1 < cnt) {
            cjt = jt[p + 1];
            cpd = edata[p + 1];
            const float* ej = eq + ((size_t)cjt.x * F_DIM + f) * 3;
            ce0 = ej[0]; ce1 = ej[1]; ce2 = ej[2];
        }

        // wave-uniform rbf coefficients (broadcast loads, 1-2 granules each)
        const float4* rp = (const float4*)(rw + (size_t)p * N_RBF);
        const float4 r0 = rp[0], r1 = rp[1], r2 = rp[2], r3 = rp[3], r4 = rp[4];
        const float rb[N_RBF] = {r0.x, r0.y, r0.z, r0.w, r1.x, r1.y, r1.z, r1.w,
                                 r2.x, r2.y, r2.z, r2.w, r3.x, r3.y, r3.z, r3.w,
                                 r4.x, r4.y, r4.z, r4.w};

        float W1 = br1, W2 = br2, W3 = br3;
#pragma unroll
        for (int n = 0; n < N_RBF; ++n) {
            const float* wr = w_rbf + n * (3 * F_DIM);   // 30 KB, L1-resident
            W1 = fmaf(rb[n], wr[f], W1);
            W2 = fmaf(rb[n], wr[F_DIM + f], W2);
            W3 = fmaf(rb[n], wr[2 * F_DIM + f], W3);
        }

        const float* pt = phi_table + t * (3 * F_DIM);
        const float phi1 = pt[f];
        const float phi2 = pt[F_DIM + f];
        const float phi3 = pt[2 * F_DIM + f];

        accE += phi1 * W1;
        const float s2 = phi2 * W2;
        const float s3 = phi3 * W3 * pd.w;

        ax = fmaf(e0, s2, fmaf(s3, pd.x, ax));
        ay = fmaf(e1, s2, fmaf(s3, pd.y, ay));
        az = fmaf(e2, s2, fmaf(s3, pd.z, az));
    }

    out_emb[(size_t)i * F_DIM + f] = emb_table[z[i] * F_DIM + f] + accE;

    const float* ei = eq     + ((size_t)i * F_DIM + f) * 3;
    float*       od = out_eq + ((size_t)i * F_DIM + f) * 3;
    od[0] = ei[0] + ax;
    od[1] = ei[1] + ay;
    od[2] = ei[2] + az;
}

// ---------------------------------------------------------------------------
extern "C" void kernel_launch(void* const* d_in, const int* in_sizes, int n_in,
                              void* d_out, int out_size, void* d_ws, size_t ws_size,
                              hipStream_t stream) {
    const float* pos       = (const float*)d_in[0];
    const float* eq        = (const float*)d_in[1];
    const float* emb_table = (const float*)d_in[2];
    const float* w_phi1    = (const float*)d_in[3];
    const float* b_phi1    = (const float*)d_in[4];
    const float* w_phi2    = (const float*)d_in[5];
    const float* b_phi2    = (const float*)d_in[6];
    const float* w_rbf     = (const float*)d_in[7];
    const float* b_rbf     = (const float*)d_in[8];
    const int*   z         = (const int*)d_in[9];
    const int*   esrc      = (const int*)d_in[10];
    const int*   edst      = (const int*)d_in[11];

    float* out_emb = (float*)d_out;                               // [N, F]
    float* out_eq  = (float*)d_out + (size_t)N_NODES * F_DIM;     // [N, F, 3]

    // workspace layout (16B-aligned chunks)
    char* ws = (char*)d_ws;
    float4* edata      = (float4*)ws;  ws += (size_t)N_EDGES * 16;
    float*  rw         = (float*)ws;   ws += (size_t)N_EDGES * N_RBF * 4;
    int2*   jt         = (int2*)ws;    ws += (size_t)N_EDGES * 8;
    float*  phi_table  = (float*)ws;   ws += 100 * 3 * F_DIM * 4;
    int*    counts     = (int*)ws;     ws += N_NODES * 4;
    int*    partial    = (int*)ws;     ws += N_NODES * 4;
    int*    offsets    = (int*)ws;     ws += N_NODES * 4;
    int*    cursor     = (int*)ws;     ws += N_NODES * 4;
    int*    chunk_sums = (int*)ws;     ws += SCAN_B * 4;
    int*    chunk_pref = (int*)ws;     ws += SCAN_B * 4;

    hipMemsetAsync(counts, 0, N_NODES * sizeof(int), stream);
    phi_table_kernel<<<100, 3 * F_DIM, 0, stream>>>(emb_table, w_phi1, b_phi1,
                                                    w_phi2, b_phi2, phi_table);
    count_kernel<<<(N_EDGES + 255) / 256, 256, 0, stream>>>(edst, counts);
    scan_partial_kernel<<<N_CHUNK, SCAN_B, 0, stream>>>(counts, partial, chunk_sums);
    scan_sums_kernel<<<1, SCAN_B, 0, stream>>>(chunk_sums, chunk_pref);
    finalize_offsets_kernel<<<(N_NODES + 255) / 256, 256, 0, stream>>>(
        partial, chunk_pref, offsets, cursor);
    edge_pre_kernel<<<(N_EDGES + 255) / 256, 256, 0, stream>>>(
        pos, z, esrc, edst, cursor, edata, jt, rw);
    gather_kernel<<<(N_NODES + 1) / 2, 256, 0, stream>>>(
        eq, emb_table, phi_table, w_rbf, b_rbf, z, edata, jt, rw,
        offsets, counts, out_emb, out_eq);
}

// Round 6
// 494.064 us; speedup vs baseline: 3.8636x; 1.1204x over previous
//
#include <hip/hip_runtime.h>
#include <math.h>

#define N_NODES 50000
#define N_EDGES 400000
#define F_DIM   128
#define N_RBF   20
#define SCAN_B  256
#define N_CHUNK ((N_NODES + SCAN_B - 1) / SCAN_B)   // 196

// ---------------------------------------------------------------------------
// phi_table[t] = silu(emb_table[t] @ w_phi1 + b_phi1) @ w_phi2 + b_phi2
// ---------------------------------------------------------------------------
__global__ void phi_table_kernel(const float* __restrict__ emb_table,
                                 const float* __restrict__ w_phi1,
                                 const float* __restrict__ b_phi1,
                                 const float* __restrict__ w_phi2,
                                 const float* __restrict__ b_phi2,
                                 float* __restrict__ phi_table) {
    __shared__ float emb_s[F_DIM];
    __shared__ float h_s[F_DIM];
    const int t = blockIdx.x;
    const int o = threadIdx.x;
    if (o < F_DIM) emb_s[o] = emb_table[t * F_DIM + o];
    __syncthreads();
    if (o < F_DIM) {
        float acc = b_phi1[o];
#pragma unroll 8
        for (int k = 0; k < F_DIM; ++k)
            acc = fmaf(emb_s[k], w_phi1[k * F_DIM + o], acc);
        h_s[o] = acc / (1.0f + expf(-acc));   // silu
    }
    __syncthreads();
    float a2 = b_phi2[o];
#pragma unroll 8
    for (int k = 0; k < F_DIM; ++k)
        a2 = fmaf(h_s[k], w_phi2[k * (3 * F_DIM) + o], a2);
    phi_table[t * (3 * F_DIM) + o] = a2;
}

__global__ void count_kernel(const int* __restrict__ edst, int* __restrict__ counts) {
    const int e = blockIdx.x * blockDim.x + threadIdx.x;
    if (e < N_EDGES) atomicAdd(&counts[edst[e]], 1);
}

__global__ void scan_partial_kernel(const int* __restrict__ counts,
                                    int* __restrict__ partial,
                                    int* __restrict__ chunk_sums) {
    __shared__ int s[SCAN_B];
    const int tid = threadIdx.x;
    const int gid = blockIdx.x * SCAN_B + tid;
    const int v = (gid < N_NODES) ? counts[gid] : 0;
    s[tid] = v;
    __syncthreads();
    for (int d = 1; d < SCAN_B; d <<= 1) {
        const int t = (tid >= d) ? s[tid - d] : 0;
        __syncthreads();
        s[tid] += t;
        __syncthreads();
    }
    if (gid < N_NODES) partial[gid] = s[tid] - v;
    if (tid == SCAN_B - 1) chunk_sums[blockIdx.x] = s[tid];
}

__global__ void scan_sums_kernel(int* __restrict__ chunk_sums,
                                 int* __restrict__ chunk_pref) {
    __shared__ int s[SCAN_B];
    const int tid = threadIdx.x;
    const int v = (tid < N_CHUNK) ? chunk_sums[tid] : 0;
    s[tid] = v;
    __syncthreads();
    for (int d = 1; d < SCAN_B; d <<= 1) {
        const int t = (tid >= d) ? s[tid - d] : 0;
        __syncthreads();
        s[tid] += t;
        __syncthreads();
    }
    if (tid < N_CHUNK) chunk_pref[tid] = s[tid] - v;
}

__global__ void finalize_offsets_kernel(const int* __restrict__ partial,
                                        const int* __restrict__ chunk_pref,
                                        int* __restrict__ offsets,
                                        int* __restrict__ cursor) {
    const int i = blockIdx.x * blockDim.x + threadIdx.x;
    if (i >= N_NODES) return;
    const int o = partial[i] + chunk_pref[i >> 8];
    offsets[i] = o;
    cursor[i]  = o;
}

// ---------------------------------------------------------------------------
// Edge-parallel precompute + CSR fill. Per edge, one 32B record at slot p:
//   rec[2p]   = (px, py, pz, d)
//   rec[2p+1] = (j, t, sin(a)/d, 2*cos(a))   [a = pi*d/5]
// Gather regenerates all 20 rbf values from the last two via the linear
// Chebyshev recurrence t_{n+1} = 2cos(a)*t_n - t_{n-1}  (seeds 0, sa/d).
// ---------------------------------------------------------------------------
__global__ void edge_pre_kernel(const float* __restrict__ pos,
                                const int* __restrict__ z,
                                const int* __restrict__ esrc,
                                const int* __restrict__ edst,
                                int* __restrict__ cursor,
                                float4* __restrict__ rec) {
    const int e = blockIdx.x * blockDim.x + threadIdx.x;
    if (e >= N_EDGES) return;
    const int j = esrc[e];
    const int i = edst[e];
    const int p = atomicAdd(&cursor[i], 1);

    const float px = pos[3 * i + 0] - pos[3 * j + 0];
    const float py = pos[3 * i + 1] - pos[3 * j + 1];
    const float pz = pos[3 * i + 2] - pos[3 * j + 2];
    const float d = sqrtf(px * px + py * py + pz * pz);
    const float inv_d = 1.0f / d;

    float sa, ca;
    sincosf(0.6283185307179586f * d, &sa, &ca);   // pi*d/5

    rec[2 * p] = make_float4(px, py, pz, d);
    float4 b;
    b.x = __int_as_float(j);
    b.y = __int_as_float(z[j]);
    b.z = sa * inv_d;
    b.w = 2.0f * ca;
    rec[2 * p + 1] = b;
}

// ---------------------------------------------------------------------------
// Gather: 128-thread group per node (2/block). Thread f owns outputs
// f, 128+f, 256+f. w_rbf columns live in 60 REGISTERS (loaded once in the
// preamble) -> the per-edge inner loop is pure VALU: 60 W-FMAs + 19
// Chebyshev FMAs, only 8 load-insts/edge (rec + eq[j] + phi[t], all
// prefetched distance-1).
// ---------------------------------------------------------------------------
__global__ void __launch_bounds__(256)
gather_kernel(const float* __restrict__ eq,
              const float* __restrict__ emb_table,
              const float* __restrict__ phi_table,
              const float* __restrict__ w_rbf,
              const float* __restrict__ b_rbf,
              const int* __restrict__ z,
              const float4* __restrict__ rec,
              const int* __restrict__ offsets,
              const int* __restrict__ counts,
              float* __restrict__ out_emb,
              float* __restrict__ out_eq) {
    const int tid = threadIdx.x;
    const int grp = tid >> 7;
    const int f   = tid & 127;
    const int i   = blockIdx.x * 2 + grp;
    if (i >= N_NODES) return;

    const int start = offsets[i];
    const int cnt   = counts[i];

    // loop-invariant weights -> registers (60 loads, once)
    float w1r[N_RBF], w2r[N_RBF], w3r[N_RBF];
#pragma unroll
    for (int n = 0; n < N_RBF; ++n) {
        const float* wr = w_rbf + n * (3 * F_DIM);
        w1r[n] = wr[f];
        w2r[n] = wr[F_DIM + f];
        w3r[n] = wr[2 * F_DIM + f];
    }
    const float br1 = b_rbf[f];
    const float br2 = b_rbf[F_DIM + f];
    const float br3 = b_rbf[2 * F_DIM + f];

    float accE = 0.f, ax = 0.f, ay = 0.f, az = 0.f;

    float4 A0, B0;
    float eq0, eq1, eq2, ph0, ph1, ph2;
    if (cnt > 0) {
        A0 = rec[2 * start];
        B0 = rec[2 * start + 1];
        const int j0 = __float_as_int(B0.x);
        const int t0 = __float_as_int(B0.y);
        const float* ej = eq + ((size_t)j0 * F_DIM + f) * 3;
        eq0 = ej[0]; eq1 = ej[1]; eq2 = ej[2];
        const float* pt = phi_table + t0 * (3 * F_DIM);
        ph0 = pt[f]; ph1 = pt[F_DIM + f]; ph2 = pt[2 * F_DIM + f];
    }

    for (int k = 0; k < cnt; ++k) {
        // prefetch next edge's record + gathers (overlaps the FMA block)
        float4 A1, B1;
        float neq0, neq1, neq2, nph0, nph1, nph2;
        if (k + 1 < cnt) {
            const int p1 = start + k + 1;
            A1 = rec[2 * p1];
            B1 = rec[2 * p1 + 1];
            const int j1 = __float_as_int(B1.x);
            const int t1 = __float_as_int(B1.y);
            const float* ej = eq + ((size_t)j1 * F_DIM + f) * 3;
            neq0 = ej[0]; neq1 = ej[1]; neq2 = ej[2];
            const float* pt = phi_table + t1 * (3 * F_DIM);
            nph0 = pt[f]; nph1 = pt[F_DIM + f]; nph2 = pt[2 * F_DIM + f];
        }

        // pure-VALU inner block: Chebyshev rbf fused into the 3 dot products
        float W1 = br1, W2 = br2, W3 = br3;
        float tm1 = 0.0f, tc = B0.z;
        const float twoc = B0.w;
#pragma unroll
        for (int n = 0; n < N_RBF; ++n) {
            W1 = fmaf(tc, w1r[n], W1);
            W2 = fmaf(tc, w2r[n], W2);
            W3 = fmaf(tc, w3r[n], W3);
            const float tn = fmaf(twoc, tc, -tm1);
            tm1 = tc; tc = tn;
        }

        accE += ph0 * W1;
        const float s2 = ph1 * W2;
        const float s3 = ph2 * W3 * A0.w;
        ax = fmaf(eq0, s2, fmaf(s3, A0.x, ax));
        ay = fmaf(eq1, s2, fmaf(s3, A0.y, ay));
        az = fmaf(eq2, s2, fmaf(s3, A0.z, az));

        if (k + 1 < cnt) {
            A0 = A1; B0 = B1;
            eq0 = neq0; eq1 = neq1; eq2 = neq2;
            ph0 = nph0; ph1 = nph1; ph2 = nph2;
        }
    }

    out_emb[(size_t)i * F_DIM + f] = emb_table[z[i] * F_DIM + f] + accE;

    const float* ei = eq     + ((size_t)i * F_DIM + f) * 3;
    float*       od = out_eq + ((size_t)i * F_DIM + f) * 3;
    od[0] = ei[0] + ax;
    od[1] = ei[1] + ay;
    od[2] = ei[2] + az;
}

// ---------------------------------------------------------------------------
extern "C" void kernel_launch(void* const* d_in, const int* in_sizes, int n_in,
                              void* d_out, int out_size, void* d_ws, size_t ws_size,
                              hipStream_t stream) {
    const float* pos       = (const float*)d_in[0];
    const float* eq        = (const float*)d_in[1];
    const float* emb_table = (const float*)d_in[2];
    const float* w_phi1    = (const float*)d_in[3];
    const float* b_phi1    = (const float*)d_in[4];
    const float* w_phi2    = (const float*)d_in[5];
    const float* b_phi2    = (const float*)d_in[6];
    const float* w_rbf     = (const float*)d_in[7];
    const float* b_rbf     = (const float*)d_in[8];
    const int*   z         = (const int*)d_in[9];
    const int*   esrc      = (const int*)d_in[10];
    const int*   edst      = (const int*)d_in[11];

    float* out_emb = (float*)d_out;                               // [N, F]
    float* out_eq  = (float*)d_out + (size_t)N_NODES * F_DIM;     // [N, F, 3]

    // workspace layout (16B-aligned chunks)
    char* ws = (char*)d_ws;
    float4* rec        = (float4*)ws;  ws += (size_t)N_EDGES * 32;
    float*  phi_table  = (float*)ws;   ws += 100 * 3 * F_DIM * 4;
    int*    counts     = (int*)ws;     ws += N_NODES * 4;
    int*    partial    = (int*)ws;     ws += N_NODES * 4;
    int*    offsets    = (int*)ws;     ws += N_NODES * 4;
    int*    cursor     = (int*)ws;     ws += N_NODES * 4;
    int*    chunk_sums = (int*)ws;     ws += SCAN_B * 4;
    int*    chunk_pref = (int*)ws;     ws += SCAN_B * 4;

    hipMemsetAsync(counts, 0, N_NODES * sizeof(int), stream);
    phi_table_kernel<<<100, 3 * F_DIM, 0, stream>>>(emb_table, w_phi1, b_phi1,
                                                    w_phi2, b_phi2, phi_table);
    count_kernel<<<(N_EDGES + 255) / 256, 256, 0, stream>>>(edst, counts);
    scan_partial_kernel<<<N_CHUNK, SCAN_B, 0, stream>>>(counts, partial, chunk_sums);
    scan_sums_kernel<<<1, SCAN_B, 0, stream>>>(chunk_sums, chunk_pref);
    finalize_offsets_kernel<<<(N_NODES + 255) / 256, 256, 0, stream>>>(
        partial, chunk_pref, offsets, cursor);
    edge_pre_kernel<<<(N_EDGES + 255) / 256, 256, 0, stream>>>(
        pos, z, esrc, edst, cursor, rec);
    gather_kernel<<<(N_NODES + 1) / 2, 256, 0, stream>>>(
        eq, emb_table, phi_table, w_rbf, b_rbf, z, rec,
        offsets, counts, out_emb, out_eq);
}